// Round 2
// baseline (299.986 us; speedup 1.0000x reference)
//
#include <hip/hip_runtime.h>
#include <math.h>
#include <limits.h>

// 4-byte-aligned float4: backend may emit global_load_dwordx4 at 12B-stride texel
// addresses; alignment annotation keeps it legal either way.
typedef float f4u __attribute__((ext_vector_type(4), aligned(4)));

// Reflection per reference: x+=0.5; x=mod(x,2S); x = x>=S ? 2S-x : x; x-=0.5; clip[0,S-1]
// Input here is already x+0.5. inv_two = 1/(2S) (exact for pow-2 S).
__device__ __forceinline__ float reflect_pre(float xr, float size, float two, float inv_two) {
    xr = xr - floorf(xr * inv_two) * two;   // floor-mod into [0, 2S)
    if (xr >= size) xr = two - xr;
    xr -= 0.5f;
    return fminf(fmaxf(xr, 0.0f), size - 1.0f);
}

// Safe 12B texel fetch via one 16B load. t = texel index within this image.
// tmax = local index of the LAST texel of the whole img allocation (only for the
// last image; INT_MAX otherwise). When t==tmax the 16B window is shifted back 4B
// so the read ends exactly at the buffer end; channels then come from lanes y/z/w.
__device__ __forceinline__ void load_texel(const float* __restrict__ base, int t, int tmax,
                                           float& c0, float& c1, float& c2) {
    int sh = (t >= tmax) ? 1 : 0;
    f4u v = *(const f4u*)(base + (long long)t * 3 - sh);
    c0 = sh ? v.y : v.x;
    c1 = sh ? v.z : v.y;
    c2 = sh ? v.w : v.z;
}

// ---------------- pass 0: per-n folded trig ----------------
__global__ void trig_kernel(const float* __restrict__ amp, const float* __restrict__ ang,
                            float* __restrict__ trig, int N, int H, int W) {
    for (int n = threadIdx.x; n < N; n += blockDim.x) {
        float a = amp[n];
        float sa, ca;
        sincosf(ang[n], &sa, &ca);
        trig[2*n]   = ca * a * ((float)W / (float)(W - 1));
        trig[2*n+1] = sa * a * ((float)H / (float)(H - 1));
    }
}

// ---------------- pass 1: dmap channel-mean (N,DH,DW,3) -> (N,DH,DW) ----------------
__global__ __launch_bounds__(256) void dmean_kernel(const float* __restrict__ dmap,
                                                    float* __restrict__ dmean,
                                                    long long ntex) {
    long long i4 = (long long)blockIdx.x * blockDim.x + threadIdx.x;
    long long tot4 = (ntex + 3) >> 2;
    if (i4 >= tot4) return;
    const float s = 1.0f / 3.0f;
    long long base = i4 * 4;
    if (base + 3 < ntex) {
        const float4* p = (const float4*)(dmap + base * 3);  // 48B-aligned
        float4 a = p[0], b = p[1], c = p[2];
        float4 m;
        m.x = (a.x + a.y + a.z) * s;
        m.y = (a.w + b.x + b.y) * s;
        m.z = (b.z + b.w + c.x) * s;
        m.w = (c.y + c.z + c.w) * s;
        *(float4*)(dmean + base) = m;
    } else {
        for (long long t = base; t < ntex; ++t) {
            const float* p = dmap + t * 3;
            dmean[t] = (p[0] + p[1] + p[2]) * s;
        }
    }
}

// ---------------- main: 4 pixels per thread ----------------
__global__ __launch_bounds__(256) void displace4_kernel(
    const float* __restrict__ img,     // N,H,W,3
    const float* __restrict__ dmean,   // N,DH,DW
    const float* __restrict__ trig,    // N,2
    float* __restrict__ out,           // N,H,W,3
    int N, int H, int W, int DH, int DW)
{
    int qW = W >> 2;                          // quarter-row length
    int k = blockIdx.x * blockDim.x + threadIdx.x;
    if (k >= qW) return;
    int h = blockIdx.y;
    int n = blockIdx.z;

    float kx = trig[2*n];
    float ky = trig[2*n+1];

    // ---- dmap mean bilinear: y-interp once, x-texels 2k-1..2k+2 ----
    float sy = 0.5f * (float)h - 0.25f;       // (h+0.5)*(DH/H)-0.5 with DH/H==1/2
    float fy = floorf(sy);
    float ty = sy - fy;
    int dy0 = max(0, min(DH - 1, (int)fy));
    int dy1 = max(0, min(DH - 1, (int)fy + 1));
    const float* r0p = dmean + ((long long)n * DH + dy0) * DW;
    const float* r1p = dmean + ((long long)n * DH + dy1) * DW;
    int xb = 2 * k - 1;
    float R[4];
    if (xb >= 0 && xb + 3 < DW) {
        f4u v0 = *(const f4u*)(r0p + xb);
        f4u v1 = *(const f4u*)(r1p + xb);
        R[0] = v0.x + ty * (v1.x - v0.x);
        R[1] = v0.y + ty * (v1.y - v0.y);
        R[2] = v0.z + ty * (v1.z - v0.z);
        R[3] = v0.w + ty * (v1.w - v0.w);
    } else {
        #pragma unroll
        for (int j = 0; j < 4; ++j) {
            int xt = max(0, min(DW - 1, xb + j));
            float a0 = r0p[xt], a1 = r1p[xt];
            R[j] = a0 + ty * (a1 - a0);
        }
    }

    float cW = (float)W / (float)(W - 1);
    float cH = (float)H / (float)(H - 1);
    float twoW = 2.0f * (float)W, twoH = 2.0f * (float)H;
    float invTwoW = 1.0f / twoW, invTwoH = 1.0f / twoH;
    float ry_base = (float)h * cH;            // iy+0.5 at dm=0

    const float* ibase = img + (long long)n * H * W * 3;
    // Only reads in the LAST image can overrun the allocation; guard that texel.
    int tmax = (n == N - 1) ? (H * W - 1) : INT_MAX;

    float oc[12];

    #pragma unroll
    for (int p = 0; p < 4; ++p) {
        int w = 4 * k + p;
        // dmap x-interp: px0:(R0,R1,.75) px1:(R1,R2,.25) px2:(R1,R2,.75) px3:(R2,R3,.25)
        int   j0 = (p == 0) ? 0 : ((p == 3) ? 2 : 1);
        float tx = (p & 1) ? 0.25f : 0.75f;
        float dm = R[j0] + tx * (R[j0 + 1] - R[j0]);

        // folded: ix+0.5 = w*W/(W-1) + dm*kx ; iy+0.5 = h*H/(H-1) + dm*ky
        float rx = (float)w * cW + dm * kx;
        float ry = ry_base     + dm * ky;
        float ix = reflect_pre(rx, (float)W, twoW, invTwoW);
        float iy = reflect_pre(ry, (float)H, twoH, invTwoH);

        float x0f = floorf(ix), y0f = floorf(iy);
        float wx = ix - x0f, wy = iy - y0f;
        int ix0 = min((int)x0f, W - 1);
        int ix1 = min(ix0 + 1, W - 1);
        int jy0 = min((int)y0f, H - 1);
        int jy1 = min(jy0 + 1, H - 1);

        int ra = jy0 * W;                     // fits int: < 2^20
        int rb = jy1 * W;

        float ax, ay, az, bx, by, bz, cx, cy, cz, dxc, dyc, dzc;
        load_texel(ibase, ra + ix0, tmax, ax, ay, az);
        load_texel(ibase, ra + ix1, tmax, bx, by, bz);
        load_texel(ibase, rb + ix0, tmax, cx, cy, cz);
        load_texel(ibase, rb + ix1, tmax, dxc, dyc, dzc);

        float wa = (1.0f - wx) * (1.0f - wy);
        float wb = wx * (1.0f - wy);
        float wc = (1.0f - wx) * wy;
        float wd = wx * wy;
        oc[p*3 + 0] = ax * wa + bx * wb + cx * wc + dxc * wd;
        oc[p*3 + 1] = ay * wa + by * wb + cy * wc + dyc * wd;
        oc[p*3 + 2] = az * wa + bz * wb + cz * wc + dzc * wd;
    }

    // 4 px * 3 ch = 48B per thread, 16B-aligned
    float4* ob = (float4*)(out + (((long long)(n * H + h) * W) + 4LL * k) * 3);
    ob[0] = make_float4(oc[0], oc[1], oc[2],  oc[3]);
    ob[1] = make_float4(oc[4], oc[5], oc[6],  oc[7]);
    ob[2] = make_float4(oc[8], oc[9], oc[10], oc[11]);
}

// ---------------- fallback: verified single-pixel kernel ----------------
__device__ __forceinline__ float reflect_coord(float x, float size) {
    x += 0.5f;
    float two = 2.0f * size;
    x = x - floorf(x / two) * two;
    if (x >= size) x = two - x;
    x -= 0.5f;
    return fminf(fmaxf(x, 0.0f), size - 1.0f);
}

__global__ __launch_bounds__(256) void displace_kernel(
    const float* __restrict__ img, const float* __restrict__ dmap,
    const float* __restrict__ amp, const float* __restrict__ ang,
    float* __restrict__ out, int N, int H, int W, int DH, int DW)
{
    long long idx = (long long)blockIdx.x * blockDim.x + threadIdx.x;
    long long total = (long long)N * H * W;
    if (idx >= total) return;
    int w = (int)(idx % W);
    long long t = idx / W;
    int h = (int)(t % H);
    int n = (int)(t / H);

    float sx = (w + 0.5f) * ((float)DW / (float)W) - 0.5f;
    float sy = (h + 0.5f) * ((float)DH / (float)H) - 0.5f;
    float fx = floorf(sx), fy = floorf(sy);
    float tx = sx - fx, ty = sy - fy;
    int dx0 = max(0, min(DW - 1, (int)fx));
    int dx1 = max(0, min(DW - 1, (int)fx + 1));
    int dy0 = max(0, min(DH - 1, (int)fy));
    int dy1 = max(0, min(DH - 1, (int)fy + 1));

    const float* dbase = dmap + (long long)n * DH * DW * 3;
    const float* p00 = dbase + ((long long)dy0 * DW + dx0) * 3;
    const float* p01 = dbase + ((long long)dy0 * DW + dx1) * 3;
    const float* p10 = dbase + ((long long)dy1 * DW + dx0) * 3;
    const float* p11 = dbase + ((long long)dy1 * DW + dx1) * 3;
    float m00 = p00[0] + p00[1] + p00[2];
    float m01 = p01[0] + p01[1] + p01[2];
    float m10 = p10[0] + p10[1] + p10[2];
    float m11 = p11[0] + p11[1] + p11[2];
    float dmv = ((m00 * (1.0f - tx) + m01 * tx) * (1.0f - ty)
               + (m10 * (1.0f - tx) + m11 * tx) * ty) * (1.0f / 3.0f);

    float a = amp[n];
    float sa, ca;
    sincosf(ang[n], &sa, &ca);
    float d = dmv * a;
    float ddx = ca * d * (2.0f / (float)(W - 1));
    float ddy = sa * d * (2.0f / (float)(H - 1));
    float gx = -1.0f + 2.0f * (float)w / (float)(W - 1) + ddx;
    float gy = -1.0f + 2.0f * (float)h / (float)(H - 1) + ddy;
    float ix = ((gx + 1.0f) * (float)W - 1.0f) * 0.5f;
    float iy = ((gy + 1.0f) * (float)H - 1.0f) * 0.5f;
    ix = reflect_coord(ix, (float)W);
    iy = reflect_coord(iy, (float)H);

    float x0f = floorf(ix), y0f = floorf(iy);
    float wx = ix - x0f, wy = iy - y0f;
    int ix0 = min((int)x0f, W - 1);
    int ix1 = min((int)x0f + 1, W - 1);
    int iy0 = min((int)y0f, H - 1);
    int iy1 = min((int)y0f + 1, H - 1);

    const float* ibase = img + (long long)n * H * W * 3;
    const float* Ia = ibase + ((long long)iy0 * W + ix0) * 3;
    const float* Ib = ibase + ((long long)iy0 * W + ix1) * 3;
    const float* Ic = ibase + ((long long)iy1 * W + ix0) * 3;
    const float* Id = ibase + ((long long)iy1 * W + ix1) * 3;
    float wa = (1.0f - wx) * (1.0f - wy);
    float wb = wx * (1.0f - wy);
    float wc = (1.0f - wx) * wy;
    float wd = wx * wy;
    float* o = out + idx * 3;
    #pragma unroll
    for (int c = 0; c < 3; ++c)
        o[c] = Ia[c] * wa + Ib[c] * wb + Ic[c] * wc + Id[c] * wd;
}

extern "C" void kernel_launch(void* const* d_in, const int* in_sizes, int n_in,
                              void* d_out, int out_size, void* d_ws, size_t ws_size,
                              hipStream_t stream) {
    const float* img  = (const float*)d_in[0];
    const float* dmap = (const float*)d_in[1];
    const float* amp  = (const float*)d_in[2];
    const float* ang  = (const float*)d_in[3];
    float* out = (float*)d_out;

    int N = in_sizes[2];
    long long hw  = (long long)in_sizes[0] / ((long long)N * 3);
    int H = (int)llround(sqrt((double)hw));
    int W = H;
    long long dhw = (long long)in_sizes[1] / ((long long)N * 3);
    int DH = (int)llround(sqrt((double)dhw));
    int DW = DH;

    // workspace layout: [trig: 2N floats][pad to 256B][dmean: N*DH*DW floats]
    size_t trig_bytes = (size_t)2 * N * sizeof(float);
    size_t off = (trig_bytes + 255) & ~(size_t)255;
    size_t need = off + (size_t)N * DH * DW * sizeof(float);
    bool fast = (W % 4 == 0) && (W == 2 * DW) && (H == 2 * DH) &&
                ((long long)H * W <= (long long)INT_MAX) &&
                d_ws != nullptr && ws_size >= need;

    if (fast) {
        float* trig  = (float*)d_ws;
        float* dmean = (float*)((char*)d_ws + off);

        trig_kernel<<<1, 256, 0, stream>>>(amp, ang, trig, N, H, W);

        long long ntex = (long long)N * DH * DW;
        long long tot4 = (ntex + 3) >> 2;
        int dblocks = (int)((tot4 + 255) / 256);
        dmean_kernel<<<dblocks, 256, 0, stream>>>(dmap, dmean, ntex);

        int qW = W >> 2;
        dim3 grid((qW + 255) / 256, H, N);
        displace4_kernel<<<grid, 256, 0, stream>>>(img, dmean, trig, out, N, H, W, DH, DW);
    } else {
        long long total = (long long)N * H * W;
        int block = 256;
        long long grid = (total + block - 1) / block;
        displace_kernel<<<(dim3)(unsigned)grid, block, 0, stream>>>(
            img, dmap, amp, ang, out, N, H, W, DH, DW);
    }
}

// Round 3
// 298.438 us; speedup vs baseline: 1.0052x; 1.0052x over previous
//
#include <hip/hip_runtime.h>
#include <math.h>
#include <limits.h>

// 4-byte-aligned float4: backend may emit global_load_dwordx4 at 12B-stride texel
// addresses; alignment annotation keeps it legal either way.
typedef float f4u __attribute__((ext_vector_type(4), aligned(4)));

// Reflection per reference: x+=0.5; x=mod(x,2S); x = x>=S ? 2S-x : x; x-=0.5; clip[0,S-1]
// Input here is already x+0.5. inv_two = 1/(2S) (exact for pow-2 S).
__device__ __forceinline__ float reflect_pre(float xr, float size, float two, float inv_two) {
    xr = xr - floorf(xr * inv_two) * two;   // floor-mod into [0, 2S)
    if (xr >= size) xr = two - xr;
    xr -= 0.5f;
    return fminf(fmaxf(xr, 0.0f), size - 1.0f);
}

// Safe 12B texel fetch via one 16B load. t = texel index within this image.
// tmax = local index of the LAST texel of the whole img allocation (only for the
// last image; INT_MAX otherwise). When t==tmax the 16B window is shifted back 4B
// so the read ends exactly at the buffer end; channels then come from lanes y/z/w.
__device__ __forceinline__ void load_texel(const float* __restrict__ base, int t, int tmax,
                                           float& c0, float& c1, float& c2) {
    int sh = (t >= tmax) ? 1 : 0;
    f4u v = *(const f4u*)(base + (long long)t * 3 - sh);
    c0 = sh ? v.y : v.x;
    c1 = sh ? v.z : v.y;
    c2 = sh ? v.w : v.z;
}

// ---------------- fused single-pass kernel: 4 pixels per thread ----------------
// 1-D grid with bijective XCD swizzle (m204): hardware ids round-robin across the
// 8 XCDs; the swizzle hands each XCD a CONTIGUOUS chunk of original (n,h) rows so
// the +-20-row gather band stays resident in that XCD's private 4MB L2.
__global__ __launch_bounds__(256) void displace_fused_kernel(
    const float* __restrict__ img,     // N,H,W,3
    const float* __restrict__ dmap,    // N,DH,DW,3
    const float* __restrict__ amp,     // N
    const float* __restrict__ ang,     // N
    float* __restrict__ out,           // N,H,W,3
    int N, int H, int W, int DH, int DW, int gx, unsigned nb)
{
    unsigned id  = blockIdx.x;
    unsigned q   = nb >> 3, r = nb & 7u;
    unsigned xcd = id & 7u, off = id >> 3;
    unsigned orig = (xcd < r) ? (xcd * (q + 1u) + off)
                              : (r * (q + 1u) + (xcd - r) * q + off);
    int kb = (int)(orig % (unsigned)gx);
    unsigned t1 = orig / (unsigned)gx;
    int h = (int)(t1 % (unsigned)H);
    int n = (int)(t1 / (unsigned)H);

    int qW = W >> 2;                          // quarter-row length
    int k = kb * 256 + (int)threadIdx.x;
    if (k >= qW) return;

    // ---- per-image constants (n uniform per block -> scalar path) ----
    float a = amp[n];
    float sa, ca;
    sincosf(ang[n], &sa, &ca);
    float cW = (float)W / (float)(W - 1);
    float cH = (float)H / (float)(H - 1);
    float kxc = ca * a * cW;                  // contribution of dm to ix+0.5
    float kyc = sa * a * cH;

    // ---- dmap mean + bilinear: y-interp once, x-texels 2k-1..2k+2 ----
    float sy = 0.5f * (float)h - 0.25f;       // (h+0.5)*(DH/H)-0.5 with DH/H==1/2
    float fy = floorf(sy);
    float ty = sy - fy;
    int dy0 = max(0, min(DH - 1, (int)fy));
    int dy1 = max(0, min(DH - 1, (int)fy + 1));
    const float* dbase = dmap + (long long)n * DH * DW * 3;
    const float* r0p = dbase + (long long)dy0 * DW * 3;
    const float* r1p = dbase + (long long)dy1 * DW * 3;
    int xb = 2 * k - 1;
    const float s3 = 1.0f / 3.0f;
    float R[4];
    if (xb >= 0 && xb + 3 < DW) {
        // 4 texels = 12 floats = 3 x f4u per row, fully in-bounds
        const f4u* q0 = (const f4u*)(r0p + (long long)xb * 3);
        const f4u* q1 = (const f4u*)(r1p + (long long)xb * 3);
        f4u a0 = q0[0], b0 = q0[1], c0 = q0[2];
        f4u a1 = q1[0], b1 = q1[1], c1 = q1[2];
        float m0a = a0.x + a0.y + a0.z, m1a = a0.w + b0.x + b0.y;
        float m2a = b0.z + b0.w + c0.x, m3a = c0.y + c0.z + c0.w;
        float m0b = a1.x + a1.y + a1.z, m1b = a1.w + b1.x + b1.y;
        float m2b = b1.z + b1.w + c1.x, m3b = c1.y + c1.z + c1.w;
        R[0] = (m0a + ty * (m0b - m0a)) * s3;
        R[1] = (m1a + ty * (m1b - m1a)) * s3;
        R[2] = (m2a + ty * (m2b - m2a)) * s3;
        R[3] = (m3a + ty * (m3b - m3a)) * s3;
    } else {
        #pragma unroll
        for (int j = 0; j < 4; ++j) {
            int xt = max(0, min(DW - 1, xb + j));
            const float* p0 = r0p + (long long)xt * 3;
            const float* p1 = r1p + (long long)xt * 3;
            float ma = p0[0] + p0[1] + p0[2];
            float mb = p1[0] + p1[1] + p1[2];
            R[j] = (ma + ty * (mb - ma)) * s3;
        }
    }

    float twoW = 2.0f * (float)W, twoH = 2.0f * (float)H;
    float invTwoW = 1.0f / twoW, invTwoH = 1.0f / twoH;
    float ry_base = (float)h * cH;            // iy+0.5 at dm=0

    const float* ibase = img + (long long)n * H * W * 3;
    // Only reads in the LAST image can overrun the allocation; guard that texel.
    int tmax = (n == N - 1) ? (H * W - 1) : INT_MAX;

    float oc[12];

    #pragma unroll
    for (int p = 0; p < 4; ++p) {
        int w = 4 * k + p;
        // dmap x-interp: px0:(R0,R1,.75) px1:(R1,R2,.25) px2:(R1,R2,.75) px3:(R2,R3,.25)
        int   j0 = (p == 0) ? 0 : ((p == 3) ? 2 : 1);
        float tx = (p & 1) ? 0.25f : 0.75f;
        float dm = R[j0] + tx * (R[j0 + 1] - R[j0]);

        // folded: ix+0.5 = w*W/(W-1) + dm*kxc ; iy+0.5 = h*H/(H-1) + dm*kyc
        float rx = (float)w * cW + dm * kxc;
        float ry = ry_base      + dm * kyc;
        float ix = reflect_pre(rx, (float)W, twoW, invTwoW);
        float iy = reflect_pre(ry, (float)H, twoH, invTwoH);

        float x0f = floorf(ix), y0f = floorf(iy);
        float wx = ix - x0f, wy = iy - y0f;
        int ix0 = min((int)x0f, W - 1);
        int ix1 = min(ix0 + 1, W - 1);
        int jy0 = min((int)y0f, H - 1);
        int jy1 = min(jy0 + 1, H - 1);

        int ra = jy0 * W;                     // fits int: < 2^20
        int rb = jy1 * W;

        float ax, ay, az, bx, by, bz, cx, cy, cz, dxc, dyc, dzc;
        load_texel(ibase, ra + ix0, tmax, ax, ay, az);
        load_texel(ibase, ra + ix1, tmax, bx, by, bz);
        load_texel(ibase, rb + ix0, tmax, cx, cy, cz);
        load_texel(ibase, rb + ix1, tmax, dxc, dyc, dzc);

        float wa = (1.0f - wx) * (1.0f - wy);
        float wb = wx * (1.0f - wy);
        float wc = (1.0f - wx) * wy;
        float wd = wx * wy;
        oc[p*3 + 0] = ax * wa + bx * wb + cx * wc + dxc * wd;
        oc[p*3 + 1] = ay * wa + by * wb + cy * wc + dyc * wd;
        oc[p*3 + 2] = az * wa + bz * wb + cz * wc + dzc * wd;
    }

    // 4 px * 3 ch = 48B per thread, 16B-aligned
    float4* ob = (float4*)(out + (((long long)(n * H + h) * W) + 4LL * k) * 3);
    ob[0] = make_float4(oc[0], oc[1], oc[2],  oc[3]);
    ob[1] = make_float4(oc[4], oc[5], oc[6],  oc[7]);
    ob[2] = make_float4(oc[8], oc[9], oc[10], oc[11]);
}

// ---------------- fallback: verified single-pixel kernel ----------------
__device__ __forceinline__ float reflect_coord(float x, float size) {
    x += 0.5f;
    float two = 2.0f * size;
    x = x - floorf(x / two) * two;
    if (x >= size) x = two - x;
    x -= 0.5f;
    return fminf(fmaxf(x, 0.0f), size - 1.0f);
}

__global__ __launch_bounds__(256) void displace_kernel(
    const float* __restrict__ img, const float* __restrict__ dmap,
    const float* __restrict__ amp, const float* __restrict__ ang,
    float* __restrict__ out, int N, int H, int W, int DH, int DW)
{
    long long idx = (long long)blockIdx.x * blockDim.x + threadIdx.x;
    long long total = (long long)N * H * W;
    if (idx >= total) return;
    int w = (int)(idx % W);
    long long t = idx / W;
    int h = (int)(t % H);
    int n = (int)(t / H);

    float sx = (w + 0.5f) * ((float)DW / (float)W) - 0.5f;
    float sy = (h + 0.5f) * ((float)DH / (float)H) - 0.5f;
    float fx = floorf(sx), fy = floorf(sy);
    float tx = sx - fx, ty = sy - fy;
    int dx0 = max(0, min(DW - 1, (int)fx));
    int dx1 = max(0, min(DW - 1, (int)fx + 1));
    int dy0 = max(0, min(DH - 1, (int)fy));
    int dy1 = max(0, min(DH - 1, (int)fy + 1));

    const float* dbase = dmap + (long long)n * DH * DW * 3;
    const float* p00 = dbase + ((long long)dy0 * DW + dx0) * 3;
    const float* p01 = dbase + ((long long)dy0 * DW + dx1) * 3;
    const float* p10 = dbase + ((long long)dy1 * DW + dx0) * 3;
    const float* p11 = dbase + ((long long)dy1 * DW + dx1) * 3;
    float m00 = p00[0] + p00[1] + p00[2];
    float m01 = p01[0] + p01[1] + p01[2];
    float m10 = p10[0] + p10[1] + p10[2];
    float m11 = p11[0] + p11[1] + p11[2];
    float dmv = ((m00 * (1.0f - tx) + m01 * tx) * (1.0f - ty)
               + (m10 * (1.0f - tx) + m11 * tx) * ty) * (1.0f / 3.0f);

    float a = amp[n];
    float sa, ca;
    sincosf(ang[n], &sa, &ca);
    float d = dmv * a;
    float ddx = ca * d * (2.0f / (float)(W - 1));
    float ddy = sa * d * (2.0f / (float)(H - 1));
    float gx = -1.0f + 2.0f * (float)w / (float)(W - 1) + ddx;
    float gy = -1.0f + 2.0f * (float)h / (float)(H - 1) + ddy;
    float ix = ((gx + 1.0f) * (float)W - 1.0f) * 0.5f;
    float iy = ((gy + 1.0f) * (float)H - 1.0f) * 0.5f;
    ix = reflect_coord(ix, (float)W);
    iy = reflect_coord(iy, (float)H);

    float x0f = floorf(ix), y0f = floorf(iy);
    float wx = ix - x0f, wy = iy - y0f;
    int ix0 = min((int)x0f, W - 1);
    int ix1 = min((int)x0f + 1, W - 1);
    int iy0 = min((int)y0f, H - 1);
    int iy1 = min((int)y0f + 1, H - 1);

    const float* ibase = img + (long long)n * H * W * 3;
    const float* Ia = ibase + ((long long)iy0 * W + ix0) * 3;
    const float* Ib = ibase + ((long long)iy0 * W + ix1) * 3;
    const float* Ic = ibase + ((long long)iy1 * W + ix0) * 3;
    const float* Id = ibase + ((long long)iy1 * W + ix1) * 3;
    float wa = (1.0f - wx) * (1.0f - wy);
    float wb = wx * (1.0f - wy);
    float wc = (1.0f - wx) * wy;
    float wd = wx * wy;
    float* o = out + idx * 3;
    #pragma unroll
    for (int c = 0; c < 3; ++c)
        o[c] = Ia[c] * wa + Ib[c] * wb + Ic[c] * wc + Id[c] * wd;
}

extern "C" void kernel_launch(void* const* d_in, const int* in_sizes, int n_in,
                              void* d_out, int out_size, void* d_ws, size_t ws_size,
                              hipStream_t stream) {
    const float* img  = (const float*)d_in[0];
    const float* dmap = (const float*)d_in[1];
    const float* amp  = (const float*)d_in[2];
    const float* ang  = (const float*)d_in[3];
    float* out = (float*)d_out;

    int N = in_sizes[2];
    long long hw  = (long long)in_sizes[0] / ((long long)N * 3);
    int H = (int)llround(sqrt((double)hw));
    int W = H;
    long long dhw = (long long)in_sizes[1] / ((long long)N * 3);
    int DH = (int)llround(sqrt((double)dhw));
    int DW = DH;

    bool fast = (W % 4 == 0) && (W == 2 * DW) && (H == 2 * DH) &&
                ((long long)H * W <= (long long)INT_MAX);

    if (fast) {
        int qW = W >> 2;
        int gx = (qW + 255) / 256;
        unsigned nb = (unsigned)((long long)gx * H * N);
        displace_fused_kernel<<<nb, 256, 0, stream>>>(
            img, dmap, amp, ang, out, N, H, W, DH, DW, gx, nb);
    } else {
        long long total = (long long)N * H * W;
        int block = 256;
        long long grid = (total + block - 1) / block;
        displace_kernel<<<(dim3)(unsigned)grid, block, 0, stream>>>(
            img, dmap, amp, ang, out, N, H, W, DH, DW);
    }
}

// Round 5
// 214.083 us; speedup vs baseline: 1.4013x; 1.3940x over previous
//
#include <hip/hip_runtime.h>
#include <math.h>
#include <limits.h>

// 4-byte-aligned vector loads: backend emits global_load_dwordx4 / dwordx2 at
// dword-aligned (not naturally-aligned) addresses — legal on CDNA.
typedef float f4u __attribute__((ext_vector_type(4), aligned(4)));
typedef float f2u __attribute__((ext_vector_type(2), aligned(4)));

// Reflection per reference: x+=0.5; x=mod(x,2S); x = x>=S ? 2S-x : x; x-=0.5; clip[0,S-1]
// Input here is already x+0.5. inv_two = 1/(2S) (exact for pow-2 S).
__device__ __forceinline__ float reflect_pre(float xr, float size, float two, float inv_two) {
    xr = xr - floorf(xr * inv_two) * two;   // floor-mod into [0, 2S)
    if (xr >= size) xr = two - xr;
    xr -= 0.5f;
    return fminf(fmaxf(xr, 0.0f), size - 1.0f);
}

// ---------------- tiled fused kernel: 64x16 tile, 4 vertical px per thread ----
// Wave = 64 x-adjacent pixels (12B pitch -> ~12 lines/gather from x) instead of
// 256-px span (~50-64 lines/gather). Block = 4 warps x 4 rows = 64x16 px.
// Bijective XCD swizzle (m204): nb=8192 -> each XCD owns exactly one image;
// consecutive blocks on an XCD sweep a row band (footprint ~900KB < 4MB L2).
__global__ __launch_bounds__(256) void displace_tile_kernel(
    const float* __restrict__ img,     // N,H,W,3
    const float* __restrict__ dmap,    // N,DH,DW,3
    const float* __restrict__ amp,     // N
    const float* __restrict__ ang,     // N
    float* __restrict__ out,           // N,H,W,3
    int N, int H, int W, int DH, int DW,
    int tiles_x, int tiles_per_img, unsigned nb)
{
    unsigned id  = blockIdx.x;
    unsigned q   = nb >> 3, r = nb & 7u;
    unsigned xcd = id & 7u, off = id >> 3;
    unsigned orig = (xcd < r) ? (xcd * (q + 1u) + off)
                              : (r * (q + 1u) + (xcd - r) * q + off);

    int n    = (int)(orig / (unsigned)tiles_per_img);
    int rem  = (int)(orig % (unsigned)tiles_per_img);
    int ty_t = rem / tiles_x;
    int tx_t = rem % tiles_x;

    int lane = (int)(threadIdx.x & 63u);
    int warp = (int)(threadIdx.x >> 6u);

    int w  = tx_t * 64 + lane;          // global x (one wave = 64 adjacent px)
    int h0 = ty_t * 16 + warp * 4;      // even always (16, 4 even)

    // ---- per-image constants (n block-uniform) ----
    float a = amp[n];
    float sa, ca;
    sincosf(ang[n], &sa, &ca);
    float cW = (float)W / (float)(W - 1);
    float cH = (float)H / (float)(H - 1);
    float kxc = ca * a * cW;            // d(ix+0.5)/d(dm)
    float kyc = sa * a * cH;

    // ---- dmap: thread needs dmap rows M-1..M+2, x-texels fx,fx+1 ----
    // h0 even => sy(p)=M-0.25+0.5p with M=h0/2: y-taps (M-1,M,.75)(M,M+1,.25)
    // (M,M+1,.75)(M+1,M+2,.25). x: sx=0.5w-0.25 -> fx=(w>>1)-1+(w&1), tx=.75/.25.
    int M  = h0 >> 1;
    int fx = (w >> 1) - 1 + (w & 1);
    float tx = (w & 1) ? 0.25f : 0.75f;
    int qd = min(max(fx, 0), DW - 2);   // window [qd, qd+1] always in-bounds
    bool hiA = (fx >= DW - 1);          // right edge: tapA = texel qd+1
    bool loB = (fx < 0);                // left edge:  tapB = texel qd

    const float* dbase = dmap + (long long)n * DH * DW * 3;
    float Rr[4];
    #pragma unroll
    for (int j = 0; j < 4; ++j) {
        int rj = min(max(M - 1 + j, 0), DH - 1);
        const float* pr = dbase + ((long long)rj * DW + qd) * 3;
        f4u v = *(const f4u*)pr;        // texel qd (3ch) + texel qd+1 ch0
        f2u u = *(const f2u*)(pr + 4);  // texel qd+1 ch1,ch2
        float mlo = v.x + v.y + v.z;
        float mhi = v.w + u.x + u.y;
        float A = hiA ? mhi : mlo;
        float B = loB ? mlo : mhi;
        Rr[j] = A + tx * (B - A);       // x-interp of per-row channel-sum
    }

    float twoW = 2.0f * (float)W, twoH = 2.0f * (float)H;
    float invTwoW = 1.0f / twoW, invTwoH = 1.0f / twoH;
    const float s3 = 1.0f / 3.0f;
    float wxv[4], wyv[4];
    const float* PA[4];
    const float* PB[4];
    bool  CL[4];
    const float* ibase = img + (long long)n * H * W * 3;

    // y-tap table for h0 even
    const int   jlo[4] = {0, 1, 1, 2};
    const float tyv[4] = {0.75f, 0.25f, 0.75f, 0.25f};

    // ---- phase A: all addresses/weights (no loads) ----
    #pragma unroll
    for (int p = 0; p < 4; ++p) {
        float Ra = Rr[jlo[p]], Rb = Rr[jlo[p] + 1];
        float dm = (Ra + tyv[p] * (Rb - Ra)) * s3;

        float rx = (float)w * cW        + dm * kxc;   // ix + 0.5
        float ry = (float)(h0 + p) * cH + dm * kyc;   // iy + 0.5
        float ix = reflect_pre(rx, (float)W, twoW, invTwoW);
        float iy = reflect_pre(ry, (float)H, twoH, invTwoH);

        float x0f = floorf(ix), y0f = floorf(iy);
        wxv[p] = ix - x0f;
        wyv[p] = iy - y0f;
        int ix0 = (int)x0f;                 // in [0, W-1] after clip
        int jy0 = (int)y0f;
        int jy1 = min(jy0 + 1, H - 1);
        int qx  = min(ix0, W - 2);          // pair window always in-bounds
        CL[p] = (ix0 > qx);                 // ix0==W-1 -> wx==0, A:=texel W-1
        PA[p] = ibase + ((long long)jy0 * W + qx) * 3;
        PB[p] = ibase + ((long long)jy1 * W + qx) * 3;
    }

    // ---- phase B: 16 gathers (4 rows x {x4,x2} x 2 y-taps), blend, store ----
    long long obase = ((long long)(n * H + h0) * W + w) * 3;
    #pragma unroll
    for (int p = 0; p < 4; ++p) {
        f4u va = *(const f4u*)PA[p];
        f2u ua = *(const f2u*)(PA[p] + 4);
        f4u vb = *(const f4u*)PB[p];
        f2u ub = *(const f2u*)(PB[p] + 4);

        float wx = wxv[p], wy = wyv[p];
        float wa = (1.0f - wx) * (1.0f - wy);
        float wb = wx * (1.0f - wy);
        float wc = (1.0f - wx) * wy;
        float wd = wx * wy;
        bool cl = CL[p];

        float A0 = cl ? va.w : va.x, A1 = cl ? ua.x : va.y, A2 = cl ? ua.y : va.z;
        float B0 = va.w,             B1 = ua.x,             B2 = ua.y;
        float C0 = cl ? vb.w : vb.x, C1 = cl ? ub.x : vb.y, C2 = cl ? ub.y : vb.z;
        float D0 = vb.w,             D1 = ub.x,             D2 = ub.y;

        float* o = out + obase + (long long)p * W * 3;
        o[0] = A0 * wa + B0 * wb + C0 * wc + D0 * wd;
        o[1] = A1 * wa + B1 * wb + C1 * wc + D1 * wd;
        o[2] = A2 * wa + B2 * wb + C2 * wc + D2 * wd;
    }
}

// ---------------- fallback: verified single-pixel kernel ----------------
__device__ __forceinline__ float reflect_coord(float x, float size) {
    x += 0.5f;
    float two = 2.0f * size;
    x = x - floorf(x / two) * two;
    if (x >= size) x = two - x;
    x -= 0.5f;
    return fminf(fmaxf(x, 0.0f), size - 1.0f);
}

__global__ __launch_bounds__(256) void displace_kernel(
    const float* __restrict__ img, const float* __restrict__ dmap,
    const float* __restrict__ amp, const float* __restrict__ ang,
    float* __restrict__ out, int N, int H, int W, int DH, int DW)
{
    long long idx = (long long)blockIdx.x * blockDim.x + threadIdx.x;
    long long total = (long long)N * H * W;
    if (idx >= total) return;
    int w = (int)(idx % W);
    long long t = idx / W;
    int h = (int)(t % H);
    int n = (int)(t / H);

    float sx = (w + 0.5f) * ((float)DW / (float)W) - 0.5f;
    float sy = (h + 0.5f) * ((float)DH / (float)H) - 0.5f;
    float fx = floorf(sx), fy = floorf(sy);
    float tx = sx - fx, ty = sy - fy;
    int dx0 = max(0, min(DW - 1, (int)fx));
    int dx1 = max(0, min(DW - 1, (int)fx + 1));
    int dy0 = max(0, min(DH - 1, (int)fy));
    int dy1 = max(0, min(DH - 1, (int)fy + 1));

    const float* dbase = dmap + (long long)n * DH * DW * 3;
    const float* p00 = dbase + ((long long)dy0 * DW + dx0) * 3;
    const float* p01 = dbase + ((long long)dy0 * DW + dx1) * 3;
    const float* p10 = dbase + ((long long)dy1 * DW + dx0) * 3;
    const float* p11 = dbase + ((long long)dy1 * DW + dx1) * 3;
    float m00 = p00[0] + p00[1] + p00[2];
    float m01 = p01[0] + p01[1] + p01[2];
    float m10 = p10[0] + p10[1] + p10[2];
    float m11 = p11[0] + p11[1] + p11[2];
    float dmv = ((m00 * (1.0f - tx) + m01 * tx) * (1.0f - ty)
               + (m10 * (1.0f - tx) + m11 * tx) * ty) * (1.0f / 3.0f);

    float a = amp[n];
    float sa, ca;
    sincosf(ang[n], &sa, &ca);
    float d = dmv * a;
    float ddx = ca * d * (2.0f / (float)(W - 1));
    float ddy = sa * d * (2.0f / (float)(H - 1));
    float gx = -1.0f + 2.0f * (float)w / (float)(W - 1) + ddx;
    float gy = -1.0f + 2.0f * (float)h / (float)(H - 1) + ddy;
    float ix = ((gx + 1.0f) * (float)W - 1.0f) * 0.5f;
    float iy = ((gy + 1.0f) * (float)H - 1.0f) * 0.5f;
    ix = reflect_coord(ix, (float)W);
    iy = reflect_coord(iy, (float)H);

    float x0f = floorf(ix), y0f = floorf(iy);
    float wx = ix - x0f, wy = iy - y0f;
    int ix0 = min((int)x0f, W - 1);
    int ix1 = min((int)x0f + 1, W - 1);
    int iy0 = min((int)y0f, H - 1);
    int iy1 = min((int)y0f + 1, H - 1);

    const float* ibase = img + (long long)n * H * W * 3;
    const float* Ia = ibase + ((long long)iy0 * W + ix0) * 3;
    const float* Ib = ibase + ((long long)iy0 * W + ix1) * 3;
    const float* Ic = ibase + ((long long)iy1 * W + ix0) * 3;
    const float* Id = ibase + ((long long)iy1 * W + ix1) * 3;
    float wa = (1.0f - wx) * (1.0f - wy);
    float wb = wx * (1.0f - wy);
    float wc = (1.0f - wx) * wy;
    float wd = wx * wy;
    float* o = out + idx * 3;
    #pragma unroll
    for (int c = 0; c < 3; ++c)
        o[c] = Ia[c] * wa + Ib[c] * wb + Ic[c] * wc + Id[c] * wd;
}

extern "C" void kernel_launch(void* const* d_in, const int* in_sizes, int n_in,
                              void* d_out, int out_size, void* d_ws, size_t ws_size,
                              hipStream_t stream) {
    const float* img  = (const float*)d_in[0];
    const float* dmap = (const float*)d_in[1];
    const float* amp  = (const float*)d_in[2];
    const float* ang  = (const float*)d_in[3];
    float* out = (float*)d_out;

    int N = in_sizes[2];
    long long hw  = (long long)in_sizes[0] / ((long long)N * 3);
    int H = (int)llround(sqrt((double)hw));
    int W = H;
    long long dhw = (long long)in_sizes[1] / ((long long)N * 3);
    int DH = (int)llround(sqrt((double)dhw));
    int DW = DH;

    bool fast = (W % 64 == 0) && (H % 16 == 0) && (W == 2 * DW) && (H == 2 * DH) &&
                (DW >= 2) && ((long long)H * W <= (long long)INT_MAX);

    if (fast) {
        int tiles_x = W / 64;
        int tiles_y = H / 16;
        int tpi = tiles_x * tiles_y;
        unsigned nb = (unsigned)((long long)tpi * N);
        displace_tile_kernel<<<nb, 256, 0, stream>>>(
            img, dmap, amp, ang, out, N, H, W, DH, DW, tiles_x, tpi, nb);
    } else {
        long long total = (long long)N * H * W;
        int block = 256;
        long long grid = (total + block - 1) / block;
        displace_kernel<<<(dim3)(unsigned)grid, block, 0, stream>>>(
            img, dmap, amp, ang, out, N, H, W, DH, DW);
    }
}

// Round 6
// 210.209 us; speedup vs baseline: 1.4271x; 1.0184x over previous
//
#include <hip/hip_runtime.h>
#include <math.h>
#include <limits.h>

// 4-byte-aligned vector loads: backend emits global_load_dwordx4 / dwordx2 at
// dword-aligned (not naturally-aligned) addresses — legal on CDNA.
typedef float f4u __attribute__((ext_vector_type(4), aligned(4)));
typedef float f2u __attribute__((ext_vector_type(2), aligned(4)));

// Reflection per reference: x+=0.5; x=mod(x,2S); x = x>=S ? 2S-x : x; x-=0.5; clip[0,S-1]
// Input here is already x+0.5. inv_two = 1/(2S) (exact for pow-2 S).
__device__ __forceinline__ float reflect_pre(float xr, float size, float two, float inv_two) {
    xr = xr - floorf(xr * inv_two) * two;   // floor-mod into [0, 2S)
    if (xr >= size) xr = two - xr;
    xr -= 0.5f;
    return fminf(fmaxf(xr, 0.0f), size - 1.0f);
}

// ---------------- tiled fused kernel: 64x16 tile, 4 vertical px per thread ----
// Wave = 64 x-adjacent pixels (12B pitch). Block = 4 warps x 4 rows = 64x16 px.
// Bijective XCD swizzle (m204). This revision batches ALL memory ops per stage:
//   stage 1: 8 dmap loads issued, sincosf/constants overlap the latency
//   stage 2: phase A computes all 8 gather addresses (no loads)
//   stage 3: 16 image gathers issued back-to-back (sched_barrier pins them)
//   stage 4: blends + stores
// -> per-wave in-flight gathers 4 -> 16 (ILP), attacks the latency-bound regime
// (81us @ VALUBusy 29%, HBM 25%, no pipe saturated).
__global__ __launch_bounds__(256) void displace_tile_kernel(
    const float* __restrict__ img,     // N,H,W,3
    const float* __restrict__ dmap,    // N,DH,DW,3
    const float* __restrict__ amp,     // N
    const float* __restrict__ ang,     // N
    float* __restrict__ out,           // N,H,W,3
    int N, int H, int W, int DH, int DW,
    int tiles_x, int tiles_per_img, unsigned nb)
{
    unsigned id  = blockIdx.x;
    unsigned q   = nb >> 3, r = nb & 7u;
    unsigned xcd = id & 7u, off = id >> 3;
    unsigned orig = (xcd < r) ? (xcd * (q + 1u) + off)
                              : (r * (q + 1u) + (xcd - r) * q + off);

    int n    = (int)(orig / (unsigned)tiles_per_img);
    int rem  = (int)(orig % (unsigned)tiles_per_img);
    int ty_t = rem / tiles_x;
    int tx_t = rem % tiles_x;

    int lane = (int)(threadIdx.x & 63u);
    int warp = (int)(threadIdx.x >> 6u);

    int w  = tx_t * 64 + lane;          // global x (one wave = 64 adjacent px)
    int h0 = ty_t * 16 + warp * 4;      // even always (16, 4 even)

    // ---- stage 1: dmap row loads FIRST (latency overlapped by trig below) ----
    // h0 even => sy(p)=M-0.25+0.5p with M=h0/2: y-taps (M-1,M,.75)(M,M+1,.25)
    // (M,M+1,.75)(M+1,M+2,.25). x: sx=0.5w-0.25 -> fx=(w>>1)-1+(w&1), tx=.75/.25.
    int M  = h0 >> 1;
    int fx = (w >> 1) - 1 + (w & 1);
    float tx = (w & 1) ? 0.25f : 0.75f;
    int qd = min(max(fx, 0), DW - 2);   // window [qd, qd+1] always in-bounds
    bool hiA = (fx >= DW - 1);          // right edge: tapA = texel qd+1
    bool loB = (fx < 0);                // left edge:  tapB = texel qd

    const float* dbase = dmap + (long long)n * DH * DW * 3;
    f4u dv[4]; f2u du[4];
    #pragma unroll
    for (int j = 0; j < 4; ++j) {
        int rj = min(max(M - 1 + j, 0), DH - 1);
        const float* pr = dbase + ((long long)rj * DW + qd) * 3;
        dv[j] = *(const f4u*)pr;        // texel qd (3ch) + texel qd+1 ch0
        du[j] = *(const f2u*)(pr + 4);  // texel qd+1 ch1,ch2
    }

    // ---- per-image constants (independent of dmap loads -> overlaps) ----
    float a = amp[n];
    float sa, ca;
    sincosf(ang[n], &sa, &ca);
    float cW = (float)W / (float)(W - 1);
    float cH = (float)H / (float)(H - 1);
    float kxc = ca * a * cW;            // d(ix+0.5)/d(dm)
    float kyc = sa * a * cH;
    float twoW = 2.0f * (float)W, twoH = 2.0f * (float)H;
    float invTwoW = 1.0f / twoW, invTwoH = 1.0f / twoH;
    const float s3 = 1.0f / 3.0f;

    // ---- Rr: x-interp of per-row channel-sum ----
    float Rr[4];
    #pragma unroll
    for (int j = 0; j < 4; ++j) {
        float mlo = dv[j].x + dv[j].y + dv[j].z;
        float mhi = dv[j].w + du[j].x + du[j].y;
        float A = hiA ? mhi : mlo;
        float B = loB ? mlo : mhi;
        Rr[j] = A + tx * (B - A);
    }

    float wxv[4], wyv[4];
    const float* PA[4];
    const float* PB[4];
    bool  CL[4];
    const float* ibase = img + (long long)n * H * W * 3;

    // y-tap table for h0 even
    const int   jlo[4] = {0, 1, 1, 2};
    const float tyv[4] = {0.75f, 0.25f, 0.75f, 0.25f};

    // ---- stage 2: all addresses/weights (no loads) ----
    #pragma unroll
    for (int p = 0; p < 4; ++p) {
        float Ra = Rr[jlo[p]], Rb = Rr[jlo[p] + 1];
        float dm = (Ra + tyv[p] * (Rb - Ra)) * s3;

        float rx = (float)w * cW        + dm * kxc;   // ix + 0.5
        float ry = (float)(h0 + p) * cH + dm * kyc;   // iy + 0.5
        float ix = reflect_pre(rx, (float)W, twoW, invTwoW);
        float iy = reflect_pre(ry, (float)H, twoH, invTwoH);

        float x0f = floorf(ix), y0f = floorf(iy);
        wxv[p] = ix - x0f;
        wyv[p] = iy - y0f;
        int ix0 = (int)x0f;                 // in [0, W-1] after clip
        int jy0 = (int)y0f;
        int jy1 = min(jy0 + 1, H - 1);
        int qx  = min(ix0, W - 2);          // pair window always in-bounds
        CL[p] = (ix0 > qx);                 // ix0==W-1 -> wx==0, A:=texel W-1
        PA[p] = ibase + ((long long)jy0 * W + qx) * 3;
        PB[p] = ibase + ((long long)jy1 * W + qx) * 3;
    }

    // ---- stage 3: ALL 16 gathers issued before any use ----
    f4u va[4], vb[4]; f2u ua[4], ub[4];
    #pragma unroll
    for (int p = 0; p < 4; ++p) {
        va[p] = *(const f4u*)PA[p];
        ua[p] = *(const f2u*)(PA[p] + 4);
        vb[p] = *(const f4u*)PB[p];
        ub[p] = *(const f2u*)(PB[p] + 4);
    }
    __builtin_amdgcn_sched_barrier(0);      // pin: no blend hoisted between loads

    // ---- stage 4: blend + store ----
    long long obase = ((long long)(n * H + h0) * W + w) * 3;
    #pragma unroll
    for (int p = 0; p < 4; ++p) {
        float wx = wxv[p], wy = wyv[p];
        float wa = (1.0f - wx) * (1.0f - wy);
        float wb = wx * (1.0f - wy);
        float wc = (1.0f - wx) * wy;
        float wd = wx * wy;
        bool cl = CL[p];

        float A0 = cl ? va[p].w : va[p].x, A1 = cl ? ua[p].x : va[p].y, A2 = cl ? ua[p].y : va[p].z;
        float B0 = va[p].w,                B1 = ua[p].x,                B2 = ua[p].y;
        float C0 = cl ? vb[p].w : vb[p].x, C1 = cl ? ub[p].x : vb[p].y, C2 = cl ? ub[p].y : vb[p].z;
        float D0 = vb[p].w,                D1 = ub[p].x,                D2 = ub[p].y;

        float* o = out + obase + (long long)p * W * 3;
        o[0] = A0 * wa + B0 * wb + C0 * wc + D0 * wd;
        o[1] = A1 * wa + B1 * wb + C1 * wc + D1 * wd;
        o[2] = A2 * wa + B2 * wb + C2 * wc + D2 * wd;
    }
}

// ---------------- fallback: verified single-pixel kernel ----------------
__device__ __forceinline__ float reflect_coord(float x, float size) {
    x += 0.5f;
    float two = 2.0f * size;
    x = x - floorf(x / two) * two;
    if (x >= size) x = two - x;
    x -= 0.5f;
    return fminf(fmaxf(x, 0.0f), size - 1.0f);
}

__global__ __launch_bounds__(256) void displace_kernel(
    const float* __restrict__ img, const float* __restrict__ dmap,
    const float* __restrict__ amp, const float* __restrict__ ang,
    float* __restrict__ out, int N, int H, int W, int DH, int DW)
{
    long long idx = (long long)blockIdx.x * blockDim.x + threadIdx.x;
    long long total = (long long)N * H * W;
    if (idx >= total) return;
    int w = (int)(idx % W);
    long long t = idx / W;
    int h = (int)(t % H);
    int n = (int)(t / H);

    float sx = (w + 0.5f) * ((float)DW / (float)W) - 0.5f;
    float sy = (h + 0.5f) * ((float)DH / (float)H) - 0.5f;
    float fx = floorf(sx), fy = floorf(sy);
    float tx = sx - fx, ty = sy - fy;
    int dx0 = max(0, min(DW - 1, (int)fx));
    int dx1 = max(0, min(DW - 1, (int)fx + 1));
    int dy0 = max(0, min(DH - 1, (int)fy));
    int dy1 = max(0, min(DH - 1, (int)fy + 1));

    const float* dbase = dmap + (long long)n * DH * DW * 3;
    const float* p00 = dbase + ((long long)dy0 * DW + dx0) * 3;
    const float* p01 = dbase + ((long long)dy0 * DW + dx1) * 3;
    const float* p10 = dbase + ((long long)dy1 * DW + dx0) * 3;
    const float* p11 = dbase + ((long long)dy1 * DW + dx1) * 3;
    float m00 = p00[0] + p00[1] + p00[2];
    float m01 = p01[0] + p01[1] + p01[2];
    float m10 = p10[0] + p10[1] + p10[2];
    float m11 = p11[0] + p11[1] + p11[2];
    float dmv = ((m00 * (1.0f - tx) + m01 * tx) * (1.0f - ty)
               + (m10 * (1.0f - tx) + m11 * tx) * ty) * (1.0f / 3.0f);

    float a = amp[n];
    float sa, ca;
    sincosf(ang[n], &sa, &ca);
    float d = dmv * a;
    float ddx = ca * d * (2.0f / (float)(W - 1));
    float ddy = sa * d * (2.0f / (float)(H - 1));
    float gx = -1.0f + 2.0f * (float)w / (float)(W - 1) + ddx;
    float gy = -1.0f + 2.0f * (float)h / (float)(H - 1) + ddy;
    float ix = ((gx + 1.0f) * (float)W - 1.0f) * 0.5f;
    float iy = ((gy + 1.0f) * (float)H - 1.0f) * 0.5f;
    ix = reflect_coord(ix, (float)W);
    iy = reflect_coord(iy, (float)H);

    float x0f = floorf(ix), y0f = floorf(iy);
    float wx = ix - x0f, wy = iy - y0f;
    int ix0 = min((int)x0f, W - 1);
    int ix1 = min((int)x0f + 1, W - 1);
    int iy0 = min((int)y0f, H - 1);
    int iy1 = min((int)y0f + 1, H - 1);

    const float* ibase = img + (long long)n * H * W * 3;
    const float* Ia = ibase + ((long long)iy0 * W + ix0) * 3;
    const float* Ib = ibase + ((long long)iy0 * W + ix1) * 3;
    const float* Ic = ibase + ((long long)iy1 * W + ix0) * 3;
    const float* Id = ibase + ((long long)iy1 * W + ix1) * 3;
    float wa = (1.0f - wx) * (1.0f - wy);
    float wb = wx * (1.0f - wy);
    float wc = (1.0f - wx) * wy;
    float wd = wx * wy;
    float* o = out + idx * 3;
    #pragma unroll
    for (int c = 0; c < 3; ++c)
        o[c] = Ia[c] * wa + Ib[c] * wb + Ic[c] * wc + Id[c] * wd;
}

extern "C" void kernel_launch(void* const* d_in, const int* in_sizes, int n_in,
                              void* d_out, int out_size, void* d_ws, size_t ws_size,
                              hipStream_t stream) {
    const float* img  = (const float*)d_in[0];
    const float* dmap = (const float*)d_in[1];
    const float* amp  = (const float*)d_in[2];
    const float* ang  = (const float*)d_in[3];
    float* out = (float*)d_out;

    int N = in_sizes[2];
    long long hw  = (long long)in_sizes[0] / ((long long)N * 3);
    int H = (int)llround(sqrt((double)hw));
    int W = H;
    long long dhw = (long long)in_sizes[1] / ((long long)N * 3);
    int DH = (int)llround(sqrt((double)dhw));
    int DW = DH;

    bool fast = (W % 64 == 0) && (H % 16 == 0) && (W == 2 * DW) && (H == 2 * DH) &&
                (DW >= 2) && ((long long)H * W <= (long long)INT_MAX);

    if (fast) {
        int tiles_x = W / 64;
        int tiles_y = H / 16;
        int tpi = tiles_x * tiles_y;
        unsigned nb = (unsigned)((long long)tpi * N);
        displace_tile_kernel<<<nb, 256, 0, stream>>>(
            img, dmap, amp, ang, out, N, H, W, DH, DW, tiles_x, tpi, nb);
    } else {
        long long total = (long long)N * H * W;
        int block = 256;
        long long grid = (total + block - 1) / block;
        displace_kernel<<<(dim3)(unsigned)grid, block, 0, stream>>>(
            img, dmap, amp, ang, out, N, H, W, DH, DW);
    }
}

// Round 7
// 208.857 us; speedup vs baseline: 1.4363x; 1.0065x over previous
//
#include <hip/hip_runtime.h>
#include <math.h>
#include <limits.h>

// 4-byte-aligned vector loads: backend emits global_load_dwordx4 / dwordx2 at
// dword-aligned (not naturally-aligned) addresses — legal on CDNA.
typedef float f4u __attribute__((ext_vector_type(4), aligned(4)));
typedef float f2u __attribute__((ext_vector_type(2), aligned(4)));

// Reflection per reference: x+=0.5; x=mod(x,2S); x = x>=S ? 2S-x : x; x-=0.5; clip[0,S-1]
// Input here is already x+0.5. inv_two = 1/(2S) (exact for pow-2 S).
__device__ __forceinline__ float reflect_pre(float xr, float size, float two, float inv_two) {
    xr = xr - floorf(xr * inv_two) * two;   // floor-mod into [0, 2S)
    if (xr >= size) xr = two - xr;
    xr -= 0.5f;
    return fminf(fmaxf(xr, 0.0f), size - 1.0f);
}

// ---------------- tiled fused kernel: 64x16 tile, 4 vertical px per thread ----
// Wave = 64 x-adjacent pixels (12B pitch). Block = 4 warps x 4 rows = 64x16 px.
// Bijective XCD swizzle (m204). Stage order: dmap loads -> constants (overlap)
// -> addresses -> ALL 16 image gathers -> blend/store.
// __launch_bounds__(256, 4): min 4 waves/EU -> VGPR cap 128 (vs default's 40).
// Round-6 evidence: VGPR=40 forced the compiler to drain vmcnt every ~4 loads,
// serializing the batched gathers into ~5-6 x 300cy rounds per wave (183K cy/CU
// / 128 waves = 1430 cy/wave). Realized occupancy was already ~4 waves/SIMD,
// so allowing 128 VGPR costs no residency and enables true 24-deep MLP.
__global__ __launch_bounds__(256, 4) void displace_tile_kernel(
    const float* __restrict__ img,     // N,H,W,3
    const float* __restrict__ dmap,    // N,DH,DW,3
    const float* __restrict__ amp,     // N
    const float* __restrict__ ang,     // N
    float* __restrict__ out,           // N,H,W,3
    int N, int H, int W, int DH, int DW,
    int tiles_x, int tiles_per_img, unsigned nb)
{
    unsigned id  = blockIdx.x;
    unsigned q   = nb >> 3, r = nb & 7u;
    unsigned xcd = id & 7u, off = id >> 3;
    unsigned orig = (xcd < r) ? (xcd * (q + 1u) + off)
                              : (r * (q + 1u) + (xcd - r) * q + off);

    int n    = (int)(orig / (unsigned)tiles_per_img);
    int rem  = (int)(orig % (unsigned)tiles_per_img);
    int ty_t = rem / tiles_x;
    int tx_t = rem % tiles_x;

    int lane = (int)(threadIdx.x & 63u);
    int warp = (int)(threadIdx.x >> 6u);

    int w  = tx_t * 64 + lane;          // global x (one wave = 64 adjacent px)
    int h0 = ty_t * 16 + warp * 4;      // even always (16, 4 even)

    // ---- stage 1: dmap row loads FIRST (latency overlapped by trig below) ----
    // h0 even => sy(p)=M-0.25+0.5p with M=h0/2: y-taps (M-1,M,.75)(M,M+1,.25)
    // (M,M+1,.75)(M+1,M+2,.25). x: sx=0.5w-0.25 -> fx=(w>>1)-1+(w&1), tx=.75/.25.
    int M  = h0 >> 1;
    int fx = (w >> 1) - 1 + (w & 1);
    float tx = (w & 1) ? 0.25f : 0.75f;
    int qd = min(max(fx, 0), DW - 2);   // window [qd, qd+1] always in-bounds
    bool hiA = (fx >= DW - 1);          // right edge: tapA = texel qd+1
    bool loB = (fx < 0);                // left edge:  tapB = texel qd

    const float* dbase = dmap + (long long)n * DH * DW * 3;
    f4u dv[4]; f2u du[4];
    #pragma unroll
    for (int j = 0; j < 4; ++j) {
        int rj = min(max(M - 1 + j, 0), DH - 1);
        const float* pr = dbase + ((long long)rj * DW + qd) * 3;
        dv[j] = *(const f4u*)pr;        // texel qd (3ch) + texel qd+1 ch0
        du[j] = *(const f2u*)(pr + 4);  // texel qd+1 ch1,ch2
    }

    // ---- per-image constants (independent of dmap loads -> overlaps) ----
    float a = amp[n];
    float sa, ca;
    sincosf(ang[n], &sa, &ca);
    float cW = (float)W / (float)(W - 1);
    float cH = (float)H / (float)(H - 1);
    float kxc = ca * a * cW;            // d(ix+0.5)/d(dm)
    float kyc = sa * a * cH;
    float twoW = 2.0f * (float)W, twoH = 2.0f * (float)H;
    float invTwoW = 1.0f / twoW, invTwoH = 1.0f / twoH;
    const float s3 = 1.0f / 3.0f;

    // ---- Rr: x-interp of per-row channel-sum ----
    float Rr[4];
    #pragma unroll
    for (int j = 0; j < 4; ++j) {
        float mlo = dv[j].x + dv[j].y + dv[j].z;
        float mhi = dv[j].w + du[j].x + du[j].y;
        float A = hiA ? mhi : mlo;
        float B = loB ? mlo : mhi;
        Rr[j] = A + tx * (B - A);
    }

    float wxv[4], wyv[4];
    const float* PA[4];
    const float* PB[4];
    bool  CL[4];
    const float* ibase = img + (long long)n * H * W * 3;

    // y-tap table for h0 even
    const int   jlo[4] = {0, 1, 1, 2};
    const float tyv[4] = {0.75f, 0.25f, 0.75f, 0.25f};

    // ---- stage 2: all addresses/weights (no loads) ----
    #pragma unroll
    for (int p = 0; p < 4; ++p) {
        float Ra = Rr[jlo[p]], Rb = Rr[jlo[p] + 1];
        float dm = (Ra + tyv[p] * (Rb - Ra)) * s3;

        float rx = (float)w * cW        + dm * kxc;   // ix + 0.5
        float ry = (float)(h0 + p) * cH + dm * kyc;   // iy + 0.5
        float ix = reflect_pre(rx, (float)W, twoW, invTwoW);
        float iy = reflect_pre(ry, (float)H, twoH, invTwoH);

        float x0f = floorf(ix), y0f = floorf(iy);
        wxv[p] = ix - x0f;
        wyv[p] = iy - y0f;
        int ix0 = (int)x0f;                 // in [0, W-1] after clip
        int jy0 = (int)y0f;
        int jy1 = min(jy0 + 1, H - 1);
        int qx  = min(ix0, W - 2);          // pair window always in-bounds
        CL[p] = (ix0 > qx);                 // ix0==W-1 -> wx==0, A:=texel W-1
        PA[p] = ibase + ((long long)jy0 * W + qx) * 3;
        PB[p] = ibase + ((long long)jy1 * W + qx) * 3;
    }

    // ---- stage 3: ALL 16 gathers issued before any use ----
    f4u va[4], vb[4]; f2u ua[4], ub[4];
    #pragma unroll
    for (int p = 0; p < 4; ++p) {
        va[p] = *(const f4u*)PA[p];
        ua[p] = *(const f2u*)(PA[p] + 4);
        vb[p] = *(const f4u*)PB[p];
        ub[p] = *(const f2u*)(PB[p] + 4);
    }
    __builtin_amdgcn_sched_barrier(0);      // pin: no blend hoisted between loads

    // ---- stage 4: blend + store ----
    long long obase = ((long long)(n * H + h0) * W + w) * 3;
    #pragma unroll
    for (int p = 0; p < 4; ++p) {
        float wx = wxv[p], wy = wyv[p];
        float wa = (1.0f - wx) * (1.0f - wy);
        float wb = wx * (1.0f - wy);
        float wc = (1.0f - wx) * wy;
        float wd = wx * wy;
        bool cl = CL[p];

        float A0 = cl ? va[p].w : va[p].x, A1 = cl ? ua[p].x : va[p].y, A2 = cl ? ua[p].y : va[p].z;
        float B0 = va[p].w,                B1 = ua[p].x,                B2 = ua[p].y;
        float C0 = cl ? vb[p].w : vb[p].x, C1 = cl ? ub[p].x : vb[p].y, C2 = cl ? ub[p].y : vb[p].z;
        float D0 = vb[p].w,                D1 = ub[p].x,                D2 = ub[p].y;

        float* o = out + obase + (long long)p * W * 3;
        o[0] = A0 * wa + B0 * wb + C0 * wc + D0 * wd;
        o[1] = A1 * wa + B1 * wb + C1 * wc + D1 * wd;
        o[2] = A2 * wa + B2 * wb + C2 * wc + D2 * wd;
    }
}

// ---------------- fallback: verified single-pixel kernel ----------------
__device__ __forceinline__ float reflect_coord(float x, float size) {
    x += 0.5f;
    float two = 2.0f * size;
    x = x - floorf(x / two) * two;
    if (x >= size) x = two - x;
    x -= 0.5f;
    return fminf(fmaxf(x, 0.0f), size - 1.0f);
}

__global__ __launch_bounds__(256) void displace_kernel(
    const float* __restrict__ img, const float* __restrict__ dmap,
    const float* __restrict__ amp, const float* __restrict__ ang,
    float* __restrict__ out, int N, int H, int W, int DH, int DW)
{
    long long idx = (long long)blockIdx.x * blockDim.x + threadIdx.x;
    long long total = (long long)N * H * W;
    if (idx >= total) return;
    int w = (int)(idx % W);
    long long t = idx / W;
    int h = (int)(t % H);
    int n = (int)(t / H);

    float sx = (w + 0.5f) * ((float)DW / (float)W) - 0.5f;
    float sy = (h + 0.5f) * ((float)DH / (float)H) - 0.5f;
    float fx = floorf(sx), fy = floorf(sy);
    float tx = sx - fx, ty = sy - fy;
    int dx0 = max(0, min(DW - 1, (int)fx));
    int dx1 = max(0, min(DW - 1, (int)fx + 1));
    int dy0 = max(0, min(DH - 1, (int)fy));
    int dy1 = max(0, min(DH - 1, (int)fy + 1));

    const float* dbase = dmap + (long long)n * DH * DW * 3;
    const float* p00 = dbase + ((long long)dy0 * DW + dx0) * 3;
    const float* p01 = dbase + ((long long)dy0 * DW + dx1) * 3;
    const float* p10 = dbase + ((long long)dy1 * DW + dx0) * 3;
    const float* p11 = dbase + ((long long)dy1 * DW + dx1) * 3;
    float m00 = p00[0] + p00[1] + p00[2];
    float m01 = p01[0] + p01[1] + p01[2];
    float m10 = p10[0] + p10[1] + p10[2];
    float m11 = p11[0] + p11[1] + p11[2];
    float dmv = ((m00 * (1.0f - tx) + m01 * tx) * (1.0f - ty)
               + (m10 * (1.0f - tx) + m11 * tx) * ty) * (1.0f / 3.0f);

    float a = amp[n];
    float sa, ca;
    sincosf(ang[n], &sa, &ca);
    float d = dmv * a;
    float ddx = ca * d * (2.0f / (float)(W - 1));
    float ddy = sa * d * (2.0f / (float)(H - 1));
    float gx = -1.0f + 2.0f * (float)w / (float)(W - 1) + ddx;
    float gy = -1.0f + 2.0f * (float)h / (float)(H - 1) + ddy;
    float ix = ((gx + 1.0f) * (float)W - 1.0f) * 0.5f;
    float iy = ((gy + 1.0f) * (float)H - 1.0f) * 0.5f;
    ix = reflect_coord(ix, (float)W);
    iy = reflect_coord(iy, (float)H);

    float x0f = floorf(ix), y0f = floorf(iy);
    float wx = ix - x0f, wy = iy - y0f;
    int ix0 = min((int)x0f, W - 1);
    int ix1 = min((int)x0f + 1, W - 1);
    int iy0 = min((int)y0f, H - 1);
    int iy1 = min((int)y0f + 1, H - 1);

    const float* ibase = img + (long long)n * H * W * 3;
    const float* Ia = ibase + ((long long)iy0 * W + ix0) * 3;
    const float* Ib = ibase + ((long long)iy0 * W + ix1) * 3;
    const float* Ic = ibase + ((long long)iy1 * W + ix0) * 3;
    const float* Id = ibase + ((long long)iy1 * W + ix1) * 3;
    float wa = (1.0f - wx) * (1.0f - wy);
    float wb = wx * (1.0f - wy);
    float wc = (1.0f - wx) * wy;
    float wd = wx * wy;
    float* o = out + idx * 3;
    #pragma unroll
    for (int c = 0; c < 3; ++c)
        o[c] = Ia[c] * wa + Ib[c] * wb + Ic[c] * wc + Id[c] * wd;
}

extern "C" void kernel_launch(void* const* d_in, const int* in_sizes, int n_in,
                              void* d_out, int out_size, void* d_ws, size_t ws_size,
                              hipStream_t stream) {
    const float* img  = (const float*)d_in[0];
    const float* dmap = (const float*)d_in[1];
    const float* amp  = (const float*)d_in[2];
    const float* ang  = (const float*)d_in[3];
    float* out = (float*)d_out;

    int N = in_sizes[2];
    long long hw  = (long long)in_sizes[0] / ((long long)N * 3);
    int H = (int)llround(sqrt((double)hw));
    int W = H;
    long long dhw = (long long)in_sizes[1] / ((long long)N * 3);
    int DH = (int)llround(sqrt((double)dhw));
    int DW = DH;

    bool fast = (W % 64 == 0) && (H % 16 == 0) && (W == 2 * DW) && (H == 2 * DH) &&
                (DW >= 2) && ((long long)H * W <= (long long)INT_MAX);

    if (fast) {
        int tiles_x = W / 64;
        int tiles_y = H / 16;
        int tpi = tiles_x * tiles_y;
        unsigned nb = (unsigned)((long long)tpi * N);
        displace_tile_kernel<<<nb, 256, 0, stream>>>(
            img, dmap, amp, ang, out, N, H, W, DH, DW, tiles_x, tpi, nb);
    } else {
        long long total = (long long)N * H * W;
        int block = 256;
        long long grid = (total + block - 1) / block;
        displace_kernel<<<(dim3)(unsigned)grid, block, 0, stream>>>(
            img, dmap, amp, ang, out, N, H, W, DH, DW);
    }
}